// Round 1
// baseline (288.679 us; speedup 1.0000x reference)
//
#include <hip/hip_runtime.h>

// MRR kernel for MI355X (gfx950).
// N_TOT = 8192 + 8192*4000 = 32,776,192 = 8192*4001 (divisible by 4 -> vec4 loads).
// ws layout: [0, 32KB): pos floats (8192); [32KB, 48KB): packed counts (2048 u64,
// 4x16-bit counters per u64; per-row total <= 4000 so 16 bits never overflow).

constexpr int N_POS = 8192;
constexpr int N_NEG = 4000;

// Pass 1: find the 8192 pos values. index is a permutation, so every slot of
// pos[] is written exactly once. Reads index (131 MB) streaming; predict_val
// only on hit (8192 scalar loads total).
__global__ __launch_bounds__(256) void scatter_pos_kernel(
    const int4* __restrict__ idx4, const float* __restrict__ pv,
    float* __restrict__ pos, int nvec) {
  int stride = gridDim.x * blockDim.x;
  for (int j = blockIdx.x * blockDim.x + threadIdx.x; j < nvec; j += stride) {
    int4 v = idx4[j];
    if (v.x < N_POS) pos[v.x] = pv[4 * j + 0];
    if (v.y < N_POS) pos[v.y] = pv[4 * j + 1];
    if (v.z < N_POS) pos[v.z] = pv[4 * j + 2];
    if (v.w < N_POS) pos[v.w] = pv[4 * j + 3];
  }
}

// Pass 2: stream index+predict_val, compare negs against LDS-staged pos,
// count per row in LDS (2 rows packed per u32, 16-bit halves), flush packed
// u64 atomics (4 rows each) to global.
__global__ __launch_bounds__(1024) void count_kernel(
    const int4* __restrict__ idx4, const float4* __restrict__ pv4,
    const float* __restrict__ pos, unsigned long long* __restrict__ cnt,
    int nvec) {
  __shared__ float pos_lds[N_POS];          // 32 KB
  __shared__ unsigned lcnt[N_POS / 2];      // 16 KB, rows 2q,2q+1 in halves
  for (int i = threadIdx.x; i < N_POS; i += blockDim.x) pos_lds[i] = pos[i];
  for (int i = threadIdx.x; i < N_POS / 2; i += blockDim.x) lcnt[i] = 0u;
  __syncthreads();

  int stride = gridDim.x * blockDim.x;
  for (int j = blockIdx.x * blockDim.x + threadIdx.x; j < nvec; j += stride) {
    int4 v = idx4[j];
    float4 x = pv4[j];
#define DO_ELEM(IV, XV)                                                  \
    if ((IV) >= N_POS) {                                                 \
      unsigned r = (unsigned)((IV) - N_POS) / (unsigned)N_NEG;           \
      if ((XV) > pos_lds[r])                                             \
        atomicAdd(&lcnt[r >> 1], 1u << ((r & 1u) * 16u));                \
    }
    DO_ELEM(v.x, x.x)
    DO_ELEM(v.y, x.y)
    DO_ELEM(v.z, x.z)
    DO_ELEM(v.w, x.w)
#undef DO_ELEM
  }
  __syncthreads();

  // Flush: u64 slot s covers rows 4s..4s+3 = lcnt[2s] | lcnt[2s+1] << 32.
  for (int s = threadIdx.x; s < N_POS / 4; s += blockDim.x) {
    unsigned long long lo = lcnt[2 * s];
    unsigned long long hi = lcnt[2 * s + 1];
    unsigned long long p = lo | (hi << 32);
    if (p) atomicAdd(&cnt[s], p);
  }
}

// Pass 3: one block. sample_mrr + mean.
__global__ __launch_bounds__(1024) void finalize_kernel(
    const unsigned long long* __restrict__ cnt, float* __restrict__ out) {
  __shared__ float wsum[16];
  int t = threadIdx.x;
  float s = 0.f;
  for (int k = 0; k < 2; ++k) {
    unsigned long long p = cnt[2 * t + k];
    int base = 8 * t + 4 * k;
#pragma unroll
    for (int e = 0; e < 4; ++e) {
      unsigned c = (unsigned)(p >> (16 * e)) & 0xFFFFu;
      float m = 1.0f / (float)(1u + c);
      out[1 + base + e] = m;
      s += m;
    }
  }
  // wave (64-lane) reduce
#pragma unroll
  for (int off = 32; off > 0; off >>= 1) s += __shfl_down(s, off, 64);
  if ((t & 63) == 0) wsum[t >> 6] = s;
  __syncthreads();
  if (t < 64) {
    float v = (t < 16) ? wsum[t] : 0.f;
#pragma unroll
    for (int off = 8; off > 0; off >>= 1) v += __shfl_down(v, off, 64);
    if (t == 0) out[0] = v / (float)N_POS;
  }
}

extern "C" void kernel_launch(void* const* d_in, const int* in_sizes, int n_in,
                              void* d_out, int out_size, void* d_ws, size_t ws_size,
                              hipStream_t stream) {
  const float* pv = (const float*)d_in[0];
  const int* idx = (const int*)d_in[1];
  float* out = (float*)d_out;

  float* pos = (float*)d_ws;
  unsigned long long* cnt =
      (unsigned long long*)((char*)d_ws + (size_t)N_POS * sizeof(float));

  int n = in_sizes[0];       // 32,776,192 (divisible by 4)
  int nvec = n / 4;

  // zero the packed counters (8192 rows * 2 bytes)
  hipMemsetAsync(cnt, 0, (size_t)N_POS * 2, stream);

  scatter_pos_kernel<<<2048, 256, 0, stream>>>((const int4*)idx, pv, pos, nvec);
  count_kernel<<<512, 1024, 0, stream>>>((const int4*)idx, (const float4*)pv,
                                         pos, cnt, nvec);
  finalize_kernel<<<1, 1024, 0, stream>>>(cnt, out);
}